// Round 1
// baseline (250.697 us; speedup 1.0000x reference)
//
#include <hip/hip_runtime.h>
#include <cstdint>

#define B_SZ   4
#define E_DIM  16
#define C_INST 24
#define HW_N   262144          // 512*512
#define NG     (HW_N / 4)      // 65536 float4 pixel-groups per (b, e)

#define DELTA_VAR  0.75f
#define DELTA_DIST 2.0f
#define ALPHA_W 1.0f
#define BETA_W  1.0f
#define GAMMA_W 0.001f

#define P1_NB   32                       // chunks per (plane, b)
#define P1_ITER (NG / (P1_NB * 256))     // 8
#define NPLANE  (E_DIM + 1)              // 17: plane 16 accumulates counts (x := 1.0)
#define P2_BX   256
#define P2_TOTAL (P2_BX * B_SZ)          // 1024 (power of two — ticket wrap trick)

// ---------------------------------------------------------------------------
// Pass 1 (R11): lane-private LDS buckets via ds_add_f32 atomics.
//  - Old code's myrow[lc.x]+=x chains serialized (compiler can't prove
//    lc.x!=lc.y -> ds_read/waitcnt/ds_write x4 per iter). atomicAdd on
//    __shared__ float emits no-return ds_add_f32: fire-and-forget, zero stalls,
//    half the LDS ops.
//  - Counts folded in as plane eg==16 accumulating 1.0 (no ballot, no global
//    atomics). Every block writes its 24 partial sums to a DISTINCT slot
//    sums_p[b][eg][chunk][c] -> no workspace zeroing dispatch needed.
// ---------------------------------------------------------------------------
__global__ __launch_bounds__(256) void pass1_kernel(
    const float* __restrict__ input, const int* __restrict__ target,
    float* __restrict__ sums_p)
{
    __shared__ float buk[256][25];       // 24 + 1 pad; odd stride spreads banks
    const int tid   = threadIdx.x;
    const int chunk = blockIdx.x;
    const int eg    = blockIdx.y;        // 0..15 dims, 16 = count plane
    const int b     = blockIdx.z;

    float* __restrict__ myrow = &buk[tid][0];
    #pragma unroll
    for (int j = 0; j < C_INST; ++j) myrow[j] = 0.f;   // own row: no sync

    const bool cntPlane = (eg == E_DIM);
    const int4* __restrict__ tgt4 = (const int4*)(target + (size_t)b * HW_N);
    const float4* __restrict__ src4 = cntPlane ? (const float4*)nullptr
        : (const float4*)(input + ((size_t)b * E_DIM + eg) * HW_N);
    const int gbase = chunk * 256 * P1_ITER + tid;

    int4   lab = tgt4[gbase];
    float4 x   = make_float4(1.f, 1.f, 1.f, 1.f);
    if (!cntPlane) x = src4[gbase];
    #pragma unroll
    for (int it = 0; it < P1_ITER; ++it) {
        const int4   lc = lab;
        const float4 xc = x;
        if (it + 1 < P1_ITER) {          // register prefetch
            lab = tgt4[gbase + (it + 1) * 256];
            if (!cntPlane) x = src4[gbase + (it + 1) * 256];
        }
        atomicAdd(&myrow[lc.x], xc.x);   // ds_add_f32: no RAW serialization
        atomicAdd(&myrow[lc.y], xc.y);
        atomicAdd(&myrow[lc.z], xc.z);
        atomicAdd(&myrow[lc.w], xc.w);
    }
    __syncthreads();

    // reduce 256 bucket rows -> 24 partial class sums; 8 threads per class
    if (tid < 8 * C_INST) {
        const int c  = tid >> 3;
        const int r0 = tid & 7;
        float s = 0.f;
        #pragma unroll
        for (int i = 0; i < 32; ++i) s += buk[8 * i + r0][c];
        s += __shfl_xor(s, 1, 64);
        s += __shfl_xor(s, 2, 64);
        s += __shfl_xor(s, 4, 64);
        if (r0 == 0)
            sums_p[(((size_t)b * NPLANE + eg) * P1_NB + chunk) * C_INST + c] = s;
    }
}

// ---------------------------------------------------------------------------
// Pass 2 (R11): variance term + FUSED final reduction (last-block ticket).
//  - mu built per block by collapsing 32 distinct chunk-slots (52 KB L2/L3
//    per block, ~2 us aggregate) — removes the old atomic/zeroed sums path.
//  - per-block partial -> distinct slot via agent-scope release store; ticket
//    fetch_add; (old+1)&1023==0 selects exactly one last block regardless of
//    the poisoned counter's garbage start value -> no zeroing dispatch.
// ---------------------------------------------------------------------------
__global__ __launch_bounds__(256) void pass2_kernel(
    const float* __restrict__ input, const int* __restrict__ target,
    const float* __restrict__ sums_p, float* __restrict__ partials,
    unsigned int* __restrict__ ticket, float* __restrict__ out)
{
    __shared__ float mu_l[C_INST][17];
    __shared__ float w_l[C_INST];
    __shared__ float redw[4];
    __shared__ float muF[B_SZ][C_INST][E_DIM];
    __shared__ float red[256];
    __shared__ int   lastFlag;
    const int tid  = threadIdx.x;
    const int lane = tid & 63;
    const int wv   = tid >> 6;
    const int b    = blockIdx.y;

    if (tid < C_INST) {
        float cv = 0.f;
        #pragma unroll
        for (int k = 0; k < P1_NB; ++k)
            cv += sums_p[(((size_t)b * NPLANE + E_DIM) * P1_NB + k) * C_INST + tid];
        w_l[tid] = (cv > 0.f) ? 1.f / cv : 0.f;
    }
    __syncthreads();
    for (int i = tid; i < E_DIM * C_INST; i += 256) {
        const int e = i / C_INST, c = i % C_INST;
        float s = 0.f;
        #pragma unroll
        for (int k = 0; k < P1_NB; ++k)
            s += sums_p[(((size_t)b * NPLANE + e) * P1_NB + k) * C_INST + c];
        mu_l[c][e] = s * w_l[c];
    }
    __syncthreads();

    const int g = blockIdx.x * 256 + tid;    // 256 blocks/batch
    const int4 lab4 = ((const int4*)(target + (size_t)b * HW_N))[g];
    const float4* __restrict__ src4 =
        (const float4*)(input + (size_t)b * E_DIM * HW_N);

    float4 xv[E_DIM];
    #pragma unroll
    for (int e = 0; e < E_DIM; ++e)
        xv[e] = src4[(size_t)e * NG + g];

    float d2[4] = {0.f, 0.f, 0.f, 0.f};
    #pragma unroll
    for (int e = 0; e < E_DIM; ++e) {
        float df;
        df = xv[e].x - mu_l[lab4.x][e]; d2[0] = fmaf(df, df, d2[0]);
        df = xv[e].y - mu_l[lab4.y][e]; d2[1] = fmaf(df, df, d2[1]);
        df = xv[e].z - mu_l[lab4.z][e]; d2[2] = fmaf(df, df, d2[2]);
        df = xv[e].w - mu_l[lab4.w][e]; d2[3] = fmaf(df, df, d2[3]);
    }

    float vloc = 0.f;
    {
        const int lp[4] = {lab4.x, lab4.y, lab4.z, lab4.w};
        #pragma unroll
        for (int p = 0; p < 4; ++p) {
            const float h = fmaxf(sqrtf(d2[p]) - DELTA_VAR, 0.f);
            vloc = fmaf(h * h, w_l[lp[p]], vloc);
        }
    }
    #pragma unroll
    for (int m = 1; m < 64; m <<= 1) vloc += __shfl_xor(vloc, m, 64);
    if (lane == 0) redw[wv] = vloc;
    __syncthreads();

    if (tid == 0) {
        const float p = redw[0] + redw[1] + redw[2] + redw[3];
        __hip_atomic_store(&partials[b * P2_BX + blockIdx.x], p,
                           __ATOMIC_RELEASE, __HIP_MEMORY_SCOPE_AGENT);
        const unsigned int old = __hip_atomic_fetch_add(
            ticket, 1u, __ATOMIC_ACQ_REL, __HIP_MEMORY_SCOPE_AGENT);
        lastFlag = (((old + 1u) & (P2_TOTAL - 1u)) == 0u);
    }
    __syncthreads();
    if (!lastFlag) return;

    // ---- final phase: exactly one block reaches here ----
    for (int i = tid; i < B_SZ * C_INST * E_DIM; i += 256) {
        const int bb = i / (C_INST * E_DIM);
        const int r  = i % (C_INST * E_DIM);
        const int e  = r / C_INST, c = r % C_INST;
        float s = 0.f, cv = 0.f;
        #pragma unroll
        for (int k = 0; k < P1_NB; ++k) {
            s  += sums_p[(((size_t)bb * NPLANE + e)     * P1_NB + k) * C_INST + c];
            cv += sums_p[(((size_t)bb * NPLANE + E_DIM) * P1_NB + k) * C_INST + c];
        }
        muF[bb][c][e] = (cv > 0.f) ? s / cv : 0.f;
    }
    __syncthreads();

    float acc = 0.f;
    // variance partials (1024 slots, 4 per thread) — acquire: cross-XCD safe
    for (int i = tid; i < P2_TOTAL; i += 256)
        acc += __hip_atomic_load(&partials[i], __ATOMIC_ACQUIRE,
                                 __HIP_MEMORY_SCOPE_AGENT)
               * (ALPHA_W / (B_SZ * C_INST));
    // regularizer
    for (int i = tid; i < B_SZ * C_INST; i += 256) {
        const int bb = i / C_INST, c = i % C_INST;
        float n2 = 0.f;
        #pragma unroll
        for (int e = 0; e < E_DIM; ++e) n2 += muF[bb][c][e] * muF[bb][c][e];
        acc += GAMMA_W * sqrtf(n2) * (1.0f / (B_SZ * C_INST));
    }
    // pairwise repulsion
    for (int i = tid; i < B_SZ * C_INST * C_INST; i += 256) {
        const int bb = i / (C_INST * C_INST);
        const int r  = i % (C_INST * C_INST);
        const int c1 = r / C_INST, c2 = r % C_INST;
        if (c1 != c2) {
            float dd = 0.f;
            #pragma unroll
            for (int e = 0; e < E_DIM; ++e) {
                const float d = muF[bb][c1][e] - muF[bb][c2][e];
                dd += d * d;
            }
            const float h = fmaxf(2.0f * DELTA_DIST - sqrtf(dd), 0.f);
            acc += BETA_W * h * h * (1.0f / (B_SZ * C_INST * (C_INST - 1)));
        }
    }

    red[tid] = acc;
    __syncthreads();
    for (int s = 128; s > 0; s >>= 1) {
        if (tid < s) red[tid] += red[tid + s];
        __syncthreads();
    }
    if (tid == 0) out[0] = red[0];
}

extern "C" void kernel_launch(void* const* d_in, const int* in_sizes, int n_in,
                              void* d_out, int out_size, void* d_ws, size_t ws_size,
                              hipStream_t stream)
{
    const float* input  = (const float*)d_in[0];
    const int*   target = (const int*)d_in[1];

    float* sums_p   = (float*)d_ws;                               // B*17*32*24
    float* partials = sums_p + (size_t)B_SZ * NPLANE * P1_NB * C_INST;  // 1024
    unsigned int* ticket = (unsigned int*)(partials + P2_TOTAL);  // 1 uint, no zeroing

    // 2 dispatches total (was 4): no memset (distinct-slot partials), no final
    // kernel (last-block ticket fusion).
    pass1_kernel<<<dim3(P1_NB, NPLANE, B_SZ), 256, 0, stream>>>(input, target, sums_p);
    pass2_kernel<<<dim3(P2_BX, B_SZ), 256, 0, stream>>>(input, target, sums_p,
                                                        partials, ticket, (float*)d_out);
}

// Round 3
// 227.162 us; speedup vs baseline: 1.1036x; 1.1036x over previous
//
#include <hip/hip_runtime.h>
#include <cstdint>

#define B_SZ   4
#define E_DIM  16
#define C_INST 24
#define HW_N   262144          // 512*512
#define NG     (HW_N / 4)      // 65536 float4 pixel-groups per (b, e)

#define DELTA_VAR  0.75f
#define DELTA_DIST 2.0f
#define ALPHA_W 1.0f
#define BETA_W  1.0f
#define GAMMA_W 0.001f

#define P1_NB   32                       // chunks per (plane, b)
#define P1_ITER (NG / (P1_NB * 256))     // 8
#define CNT_PL  8                        // planes 0..7 emit count partials (it==eg slice)
#define P2_BX   256
#define P2_TOTAL (P2_BX * B_SZ)          // 1024 (power of two — ticket wrap trick)

// ---------------------------------------------------------------------------
// Pass 1 (R13 == R12): register select-accumulate, 24 VGPR class accumulators.
// acc[c] += (lab==c ? x : 0) per component — all independent, pure VALU
// throughput (~15us arithmetic), zero LDS in the hot loop.
// Counts via the R10-proven ballot path (planes 0..7 count slice it==eg).
// All partials to DISTINCT slots -> no workspace zeroing dispatch.
// ---------------------------------------------------------------------------
__global__ __launch_bounds__(256) void pass1_kernel(
    const float* __restrict__ input, const int* __restrict__ target,
    float* __restrict__ sums_p, float* __restrict__ cnt_p)
{
    __shared__ float wrow[4][C_INST];
    __shared__ float crow[4][C_INST];
    const int tid   = threadIdx.x;
    const int lane  = tid & 63;
    const int wv    = tid >> 6;
    const int chunk = blockIdx.x;
    const int eg    = blockIdx.y;        // 0..15 = embedding dim
    const int b     = blockIdx.z;

    const int4* __restrict__ tgt4 = (const int4*)(target + (size_t)b * HW_N);
    const float4* __restrict__ src4 =
        (const float4*)(input + ((size_t)b * E_DIM + eg) * HW_N);
    const int gbase = chunk * 256 * P1_ITER + tid;

    float acc[C_INST];
    #pragma unroll
    for (int c = 0; c < C_INST; ++c) acc[c] = 0.f;
    int scnt[C_INST];                    // wave-uniform (ballot) -> SGPRs
    #pragma unroll
    for (int c = 0; c < C_INST; ++c) scnt[c] = 0;

    int4   lab = tgt4[gbase];
    float4 x   = src4[gbase];
    #pragma unroll
    for (int it = 0; it < P1_ITER; ++it) {
        const int4   lc = lab;
        const float4 xc = x;
        if (it + 1 < P1_ITER) {          // register prefetch
            lab = tgt4[gbase + (it + 1) * 256];
            x   = src4[gbase + (it + 1) * 256];
        }
        #pragma unroll
        for (int c = 0; c < C_INST; ++c) {
            const float s0 = (lc.x == c) ? xc.x : 0.f;
            const float s1 = (lc.y == c) ? xc.y : 0.f;
            const float s2 = (lc.z == c) ? xc.z : 0.f;
            const float s3 = (lc.w == c) ? xc.w : 0.f;
            acc[c] += (s0 + s1) + (s2 + s3);
        }
        if (eg < CNT_PL && it == eg) {   // uniform branch: count this slice once
            #pragma unroll
            for (int c = 0; c < C_INST; ++c) {
                scnt[c] += (int)__popcll(__ballot(lc.x == c))
                         + (int)__popcll(__ballot(lc.y == c))
                         + (int)__popcll(__ballot(lc.z == c))
                         + (int)__popcll(__ballot(lc.w == c));
            }
        }
    }

    // wave-level tree reduce each class accumulator (one-time cost)
    #pragma unroll
    for (int c = 0; c < C_INST; ++c) {
        float v = acc[c];
        #pragma unroll
        for (int m = 1; m < 64; m <<= 1) v += __shfl_xor(v, m, 64);
        acc[c] = v;
    }
    if (lane == 0) {
        #pragma unroll
        for (int c = 0; c < C_INST; ++c) wrow[wv][c] = acc[c];
        if (eg < CNT_PL) {
            #pragma unroll
            for (int c = 0; c < C_INST; ++c) crow[wv][c] = (float)scnt[c];
        }
    }
    __syncthreads();
    if (tid < C_INST) {
        const float s = wrow[0][tid] + wrow[1][tid] + wrow[2][tid] + wrow[3][tid];
        sums_p[(((size_t)b * E_DIM + eg) * P1_NB + chunk) * C_INST + tid] = s;
        if (eg < CNT_PL) {
            const float cs = crow[0][tid] + crow[1][tid] + crow[2][tid] + crow[3][tid];
            cnt_p[(((size_t)b * CNT_PL + eg) * P1_NB + chunk) * C_INST + tid] = cs;
        }
    }
}

// ---------------------------------------------------------------------------
// Pass 2 (R13): variance term + FUSED final (last-block ticket, validated R11).
// R12 post-mortem: the mu_ws intra-kernel export (plain stores read by the
// winner block on another XCD) is the only unsound memory edge — Guideline 16:
// plain stores sit in the writer XCD's L2; only atomic locations take the
// coherent path. REMOVED. The winner block re-derives mu from sums_p/cnt_p
// (previous-kernel outputs — kernel boundary guarantees visibility; this is
// the exact R11-validated pattern). partials stay atomic release/acquire.
// ---------------------------------------------------------------------------
__global__ __launch_bounds__(256) void pass2_kernel(
    const float* __restrict__ input, const int* __restrict__ target,
    const float* __restrict__ sums_p, const float* __restrict__ cnt_p,
    float* __restrict__ partials, unsigned int* __restrict__ ticket,
    float* __restrict__ out)
{
    __shared__ float mu_l[C_INST][17];
    __shared__ float w_l[C_INST];
    __shared__ float redw[4];
    __shared__ float muF[B_SZ][C_INST][E_DIM];
    __shared__ float cntF[B_SZ][C_INST];
    __shared__ float red[256];
    __shared__ int   lastFlag;
    const int tid  = threadIdx.x;
    const int lane = tid & 63;
    const int wv   = tid >> 6;
    const int b    = blockIdx.y;

    // counts: 8 threads per class (one pass1-plane each), 32 chunks, shfl fold
    if (tid < CNT_PL * C_INST) {         // 192 threads, waves 0..2 fully active
        const int c = tid >> 3, p = tid & 7;
        float cv = 0.f;
        #pragma unroll
        for (int k = 0; k < P1_NB; ++k)
            cv += cnt_p[(((size_t)b * CNT_PL + p) * P1_NB + k) * C_INST + c];
        cv += __shfl_xor(cv, 1, 64);
        cv += __shfl_xor(cv, 2, 64);
        cv += __shfl_xor(cv, 4, 64);
        if (p == 0) w_l[c] = (cv > 0.f) ? 1.f / cv : 0.f;
    }
    __syncthreads();
    for (int i = tid; i < E_DIM * C_INST; i += 256) {
        const int e = i / C_INST, c = i % C_INST;
        float s = 0.f;
        #pragma unroll
        for (int k = 0; k < P1_NB; ++k)
            s += sums_p[(((size_t)b * E_DIM + e) * P1_NB + k) * C_INST + c];
        mu_l[c][e] = s * w_l[c];
    }
    __syncthreads();

    const int g = blockIdx.x * 256 + tid;    // 256 blocks/batch
    const int4 lab4 = ((const int4*)(target + (size_t)b * HW_N))[g];
    const float4* __restrict__ src4 =
        (const float4*)(input + (size_t)b * E_DIM * HW_N);

    float4 xv[E_DIM];
    #pragma unroll
    for (int e = 0; e < E_DIM; ++e)
        xv[e] = src4[(size_t)e * NG + g];

    float d2[4] = {0.f, 0.f, 0.f, 0.f};
    #pragma unroll
    for (int e = 0; e < E_DIM; ++e) {
        float df;
        df = xv[e].x - mu_l[lab4.x][e]; d2[0] = fmaf(df, df, d2[0]);
        df = xv[e].y - mu_l[lab4.y][e]; d2[1] = fmaf(df, df, d2[1]);
        df = xv[e].z - mu_l[lab4.z][e]; d2[2] = fmaf(df, df, d2[2]);
        df = xv[e].w - mu_l[lab4.w][e]; d2[3] = fmaf(df, df, d2[3]);
    }

    float vloc = 0.f;
    {
        const int lp[4] = {lab4.x, lab4.y, lab4.z, lab4.w};
        #pragma unroll
        for (int p = 0; p < 4; ++p) {
            const float h = fmaxf(sqrtf(d2[p]) - DELTA_VAR, 0.f);
            vloc = fmaf(h * h, w_l[lp[p]], vloc);
        }
    }
    #pragma unroll
    for (int m = 1; m < 64; m <<= 1) vloc += __shfl_xor(vloc, m, 64);
    if (lane == 0) redw[wv] = vloc;
    __syncthreads();

    if (tid == 0) {
        const float p = redw[0] + redw[1] + redw[2] + redw[3];
        __hip_atomic_store(&partials[b * P2_BX + blockIdx.x], p,
                           __ATOMIC_RELEASE, __HIP_MEMORY_SCOPE_AGENT);
        const unsigned int old = __hip_atomic_fetch_add(
            ticket, 1u, __ATOMIC_ACQ_REL, __HIP_MEMORY_SCOPE_AGENT);
        lastFlag = (((old + 1u) & (P2_TOTAL - 1u)) == 0u);
    }
    __syncthreads();
    if (!lastFlag) return;

    // ---- final phase: exactly one block; reads only pass1 outputs (safe)
    // ---- + atomic partials (validated). No intra-kernel plain-store edges.
    for (int i = tid; i < B_SZ * C_INST; i += 256) {   // 96 count totals
        const int bb = i / C_INST, c = i % C_INST;
        float cv = 0.f;
        for (int p = 0; p < CNT_PL; ++p)
            #pragma unroll
            for (int k = 0; k < P1_NB; ++k)
                cv += cnt_p[(((size_t)bb * CNT_PL + p) * P1_NB + k) * C_INST + c];
        cntF[bb][c] = cv;
    }
    __syncthreads();
    for (int i = tid; i < B_SZ * C_INST * E_DIM; i += 256) {
        const int bb = i / (C_INST * E_DIM);
        const int r  = i % (C_INST * E_DIM);
        const int e  = r / C_INST, c = r % C_INST;
        float s = 0.f;
        #pragma unroll
        for (int k = 0; k < P1_NB; ++k)
            s += sums_p[(((size_t)bb * E_DIM + e) * P1_NB + k) * C_INST + c];
        const float cv = cntF[bb][c];
        muF[bb][c][e] = (cv > 0.f) ? s / cv : 0.f;
    }
    __syncthreads();

    float acc = 0.f;
    // variance partials (1024 slots) — acquire loads: cross-XCD safe
    for (int i = tid; i < P2_TOTAL; i += 256)
        acc += __hip_atomic_load(&partials[i], __ATOMIC_ACQUIRE,
                                 __HIP_MEMORY_SCOPE_AGENT)
               * (ALPHA_W / (B_SZ * C_INST));
    // regularizer
    for (int i = tid; i < B_SZ * C_INST; i += 256) {
        const int bb = i / C_INST, c = i % C_INST;
        float n2 = 0.f;
        #pragma unroll
        for (int e = 0; e < E_DIM; ++e) n2 += muF[bb][c][e] * muF[bb][c][e];
        acc += GAMMA_W * sqrtf(n2) * (1.0f / (B_SZ * C_INST));
    }
    // pairwise repulsion
    for (int i = tid; i < B_SZ * C_INST * C_INST; i += 256) {
        const int bb = i / (C_INST * C_INST);
        const int r  = i % (C_INST * C_INST);
        const int c1 = r / C_INST, c2 = r % C_INST;
        if (c1 != c2) {
            float dd = 0.f;
            #pragma unroll
            for (int e = 0; e < E_DIM; ++e) {
                const float d = muF[bb][c1][e] - muF[bb][c2][e];
                dd += d * d;
            }
            const float h = fmaxf(2.0f * DELTA_DIST - sqrtf(dd), 0.f);
            acc += BETA_W * h * h * (1.0f / (B_SZ * C_INST * (C_INST - 1)));
        }
    }

    red[tid] = acc;
    __syncthreads();
    for (int s = 128; s > 0; s >>= 1) {
        if (tid < s) red[tid] += red[tid + s];
        __syncthreads();
    }
    if (tid == 0) out[0] = red[0];
}

extern "C" void kernel_launch(void* const* d_in, const int* in_sizes, int n_in,
                              void* d_out, int out_size, void* d_ws, size_t ws_size,
                              hipStream_t stream)
{
    const float* input  = (const float*)d_in[0];
    const int*   target = (const int*)d_in[1];

    float* sums_p = (float*)d_ws;                                    // 4*16*32*24
    float* cnt_p  = sums_p + (size_t)B_SZ * E_DIM * P1_NB * C_INST;  // 4*8*32*24
    float* partials = cnt_p + (size_t)B_SZ * CNT_PL * P1_NB * C_INST; // 1024
    unsigned int* ticket = (unsigned int*)(partials + P2_TOTAL);     // 1 uint

    // 2 dispatches, no memset (all slots distinct & rewritten every launch).
    pass1_kernel<<<dim3(P1_NB, E_DIM, B_SZ), 256, 0, stream>>>(input, target,
                                                               sums_p, cnt_p);
    pass2_kernel<<<dim3(P2_BX, B_SZ), 256, 0, stream>>>(input, target, sums_p,
                                                        cnt_p, partials,
                                                        ticket, (float*)d_out);
}

// Round 4
// 157.600 us; speedup vs baseline: 1.5907x; 1.4414x over previous
//
#include <hip/hip_runtime.h>
#include <cstdint>

#define B_SZ   4
#define E_DIM  16
#define C_INST 24
#define HW_N   262144          // 512*512
#define NG2    (HW_N / 2)      // 131072 float2 pixel-pairs per (b, e)

#define DELTA_VAR  0.75f
#define DELTA_DIST 2.0f
#define ALPHA_W 1.0f
#define BETA_W  1.0f
#define GAMMA_W 0.001f

#define P1_NB   128                      // chunks per (plane, b) — R14: 1 px/thread
#define P1_ITER (HW_N / (P1_NB * 256))   // 8
#define CNT_PL  8                        // planes 0..7 count slice it==eg
#define P2_BX   512                      // R14: 2x blocks (float2/thread) for occupancy
#define P2_TOTAL (P2_BX * B_SZ)          // 2048

// ---------------------------------------------------------------------------
// Pass 1 (R14): R10's proven LDS-bucket algorithm at 1 pixel/thread.
// R10 (float4/thread) serialized 4 LDS RMWs per iter (aliasing unknown to the
// compiler -> read/wait/add/write x4, ~520 cyc chain depth per iter, 40us).
// One dword pixel per thread -> 1 RMW/iter (chain /4); total LDS ops,
// occupancy (25.6KB -> 6 blocks/CU) and output machinery unchanged.
// [R11/R13 lessons: LDS fp atomics = 99us; 24-reg select-accumulate = 60-80us
//  — both abandoned on measurement.]
// ---------------------------------------------------------------------------
__global__ __launch_bounds__(256) void pass1_kernel(
    const float* __restrict__ input, const int* __restrict__ target,
    float* __restrict__ sums, float* __restrict__ counts)
{
    __shared__ float buk[256][25];       // 24 + 1 pad; stride 25 words: gcd(25,32)=1
    __shared__ float crow[4][C_INST];
    const int tid   = threadIdx.x;
    const int lane  = tid & 63;
    const int wv    = tid >> 6;
    const int chunk = blockIdx.x;
    const int eg    = blockIdx.y;        // 0..15 = embedding dim
    const int b     = blockIdx.z;

    float* __restrict__ myrow = &buk[tid][0];
    #pragma unroll
    for (int j = 0; j < C_INST; ++j) myrow[j] = 0.f;   // own row: no sync

    const int* __restrict__ tgt = target + (size_t)b * HW_N;
    const float* __restrict__ src = input + ((size_t)b * E_DIM + eg) * HW_N;
    const int gbase = chunk * 256 * P1_ITER + tid;

    int scnt[C_INST];
    #pragma unroll
    for (int c = 0; c < C_INST; ++c) scnt[c] = 0;

    int   lab = tgt[gbase];
    float x   = src[gbase];
    #pragma unroll
    for (int it = 0; it < P1_ITER; ++it) {
        const int   lc = lab;
        const float xc = x;
        if (it + 1 < P1_ITER) {          // register prefetch
            lab = tgt[gbase + (it + 1) * 256];
            x   = src[gbase + (it + 1) * 256];
        }
        myrow[lc] += xc;                 // single RMW: chain depth 1 per iter
        if (eg < CNT_PL && it == eg) {   // uniform branch: count this slice once
            #pragma unroll
            for (int c = 0; c < C_INST; ++c)
                scnt[c] += (int)__popcll(__ballot(lc == c));
        }
    }
    if (lane == 0) {
        #pragma unroll
        for (int c = 0; c < C_INST; ++c) crow[wv][c] = (float)scnt[c];
    }
    __syncthreads();

    // reduce 256 bucket rows -> 24 class sums; 8 threads per class (R10-proven)
    if (tid < 8 * C_INST) {
        const int c  = tid >> 3;
        const int r0 = tid & 7;
        float s = 0.f;
        #pragma unroll
        for (int i = 0; i < 32; ++i) s += buk[8 * i + r0][c];
        s += __shfl_xor(s, 1, 64);
        s += __shfl_xor(s, 2, 64);
        s += __shfl_xor(s, 4, 64);
        if (r0 == 0)
            unsafeAtomicAdd(&sums[((size_t)b * E_DIM + eg) * C_INST + c], s);
    }
    if (eg < CNT_PL && tid < C_INST) {
        const float s = crow[0][tid] + crow[1][tid] + crow[2][tid] + crow[3][tid];
        unsafeAtomicAdd(&counts[b * C_INST + tid], s);
    }
}

// ---------------------------------------------------------------------------
// Pass 2 (R14): R10's proven body at float2/thread with 2x blocks.
// R13 measured Occupancy 25%, all pipes idle -> latency uncovered. 512
// blocks/batch -> 8 blocks/CU (32 waves). mu read from atomic-built sums
// (cheap, R10-proven — NOT the 32-chunk reassembly, which cost ~15us/launch).
// Per-block partial to a DISTINCT slot; plain store (read by a later kernel
// — kernel boundary = visibility; no agent atomics).
// ---------------------------------------------------------------------------
__global__ __launch_bounds__(256) void pass2_kernel(
    const float* __restrict__ input, const int* __restrict__ target,
    const float* __restrict__ sums, const float* __restrict__ counts,
    float* __restrict__ partials)
{
    __shared__ float mu_l[C_INST][17];
    __shared__ float w_l[C_INST];
    __shared__ float redw[4];
    const int tid  = threadIdx.x;
    const int lane = tid & 63;
    const int wv   = tid >> 6;
    const int b    = blockIdx.y;

    if (tid < C_INST) {
        const float cv = counts[b * C_INST + tid];
        w_l[tid] = (cv > 0.f) ? 1.f / cv : 0.f;
    }
    __syncthreads();
    for (int i = tid; i < E_DIM * C_INST; i += 256) {
        const int e = i / C_INST, c = i % C_INST;
        mu_l[c][e] = sums[((size_t)b * E_DIM + e) * C_INST + c] * w_l[c];
    }
    __syncthreads();

    const int g = blockIdx.x * 256 + tid;    // 512 blocks/batch, float2 groups
    const int2 lab2 = ((const int2*)(target + (size_t)b * HW_N))[g];
    const float2* __restrict__ src2 =
        (const float2*)(input + (size_t)b * E_DIM * HW_N);

    float2 xv[E_DIM];
    #pragma unroll
    for (int e = 0; e < E_DIM; ++e)
        xv[e] = src2[(size_t)e * NG2 + g];

    float d2[2] = {0.f, 0.f};
    #pragma unroll
    for (int e = 0; e < E_DIM; ++e) {
        float df;
        df = xv[e].x - mu_l[lab2.x][e]; d2[0] = fmaf(df, df, d2[0]);
        df = xv[e].y - mu_l[lab2.y][e]; d2[1] = fmaf(df, df, d2[1]);
    }

    float vloc = 0.f;
    {
        const int lp[2] = {lab2.x, lab2.y};
        #pragma unroll
        for (int p = 0; p < 2; ++p) {
            const float h = fmaxf(sqrtf(d2[p]) - DELTA_VAR, 0.f);
            vloc = fmaf(h * h, w_l[lp[p]], vloc);
        }
    }
    #pragma unroll
    for (int m = 1; m < 64; m <<= 1) vloc += __shfl_xor(vloc, m, 64);
    if (lane == 0) redw[wv] = vloc;
    __syncthreads();
    if (tid == 0)
        partials[b * P2_BX + blockIdx.x] = redw[0] + redw[1] + redw[2] + redw[3];
}

// ---------------------------------------------------------------------------
// Final (R10-proven): sum 2048 partials + pairwise distance + regularizer.
// ---------------------------------------------------------------------------
__global__ __launch_bounds__(256) void final_kernel(
    const float* __restrict__ sums, const float* __restrict__ counts,
    const float* __restrict__ partials, float* __restrict__ out)
{
    __shared__ float mu[B_SZ][C_INST][E_DIM];
    __shared__ float red[256];
    const int tid = threadIdx.x;

    for (int i = tid; i < B_SZ * C_INST * E_DIM; i += 256) {
        const int b = i / (C_INST * E_DIM);
        const int r = i % (C_INST * E_DIM);
        const int e = r / C_INST, c = r % C_INST;
        const float cv = counts[b * C_INST + c];
        mu[b][c][e] = (cv > 0.f)
            ? sums[((size_t)b * E_DIM + e) * C_INST + c] / cv : 0.f;
    }
    __syncthreads();

    float acc = 0.f;
    // variance partials (2048 slots, 8 per thread)
    #pragma unroll
    for (int i = 0; i < P2_TOTAL / 256; ++i)
        acc += partials[i * 256 + tid] * (ALPHA_W / (B_SZ * C_INST));
    // regularizer
    for (int i = tid; i < B_SZ * C_INST; i += 256) {
        const int b = i / C_INST, c = i % C_INST;
        float n2 = 0.f;
        #pragma unroll
        for (int e = 0; e < E_DIM; ++e) n2 += mu[b][c][e] * mu[b][c][e];
        acc += GAMMA_W * sqrtf(n2) * (1.0f / (B_SZ * C_INST));
    }
    // pairwise repulsion
    for (int i = tid; i < B_SZ * C_INST * C_INST; i += 256) {
        const int b  = i / (C_INST * C_INST);
        const int r  = i % (C_INST * C_INST);
        const int c1 = r / C_INST, c2 = r % C_INST;
        if (c1 != c2) {
            float d2 = 0.f;
            #pragma unroll
            for (int e = 0; e < E_DIM; ++e) {
                const float d = mu[b][c1][e] - mu[b][c2][e];
                d2 += d * d;
            }
            const float h = fmaxf(2.0f * DELTA_DIST - sqrtf(d2), 0.f);
            acc += BETA_W * h * h * (1.0f / (B_SZ * C_INST * (C_INST - 1)));
        }
    }

    red[tid] = acc;
    __syncthreads();
    for (int s = 128; s > 0; s >>= 1) {
        if (tid < s) red[tid] += red[tid + s];
        __syncthreads();
    }
    if (tid == 0) out[0] = red[0];
}

extern "C" void kernel_launch(void* const* d_in, const int* in_sizes, int n_in,
                              void* d_out, int out_size, void* d_ws, size_t ws_size,
                              hipStream_t stream)
{
    const float* input  = (const float*)d_in[0];
    const int*   target = (const int*)d_in[1];

    float* sums     = (float*)d_ws;                         // B*E*C ([b][e][c])
    float* counts   = sums + B_SZ * E_DIM * C_INST;         // B*C
    float* partials = counts + B_SZ * C_INST;               // 2048 (distinct slots)
    const size_t ws_zero_bytes =
        (size_t)(B_SZ * E_DIM * C_INST + B_SZ * C_INST) * sizeof(float);
    hipMemsetAsync(d_ws, 0, ws_zero_bytes, stream);

    pass1_kernel<<<dim3(P1_NB, E_DIM, B_SZ), 256, 0, stream>>>(input, target, sums, counts);
    pass2_kernel<<<dim3(P2_BX, B_SZ), 256, 0, stream>>>(input, target, sums, counts, partials);
    final_kernel<<<1, 256, 0, stream>>>(sums, counts, partials, (float*)d_out);
}

// Round 5
// 119.232 us; speedup vs baseline: 2.1026x; 1.3218x over previous
//
#include <hip/hip_runtime.h>
#include <cstdint>

#define B_SZ   4
#define E_DIM  16
#define C_INST 24
#define HW_N   262144          // 512*512
#define NG     (HW_N / 4)      // 65536 float4 pixel-groups per (b, e)

#define DELTA_VAR  0.75f
#define DELTA_DIST 2.0f
#define ALPHA_W 1.0f
#define BETA_W  1.0f
#define GAMMA_W 0.001f

#define P1_NB   32                       // chunks per (plane, b) — R10-proven geometry
#define P1_ITER (NG / (P1_NB * 256))     // 8
#define CNT_PL  8                        // planes 0..7 count slice it==eg
#define P2_BX   256                      // R0-proven geometry (float4/thread)
#define P2_TOTAL (P2_BX * B_SZ)          // 1024

// ---------------------------------------------------------------------------
// Pass 1 (R15): R10 float4 geometry + CONFLICT-FREE bucket layout + prefetch 2.
//  - buk[C][256]: column tid is thread-private; bank = tid%32 for EVERY access
//    (init, RMW, any label) -> lanes i,i+32 alias 2-way = free (m136). R14
//    measured 4.2M conflict cycles on the old (25*tid+lc)%32 layout.
//  - prefetch depth 2: R14 counters (VALUBusy 11%, HBM 7.5%, occupancy 44%,
//    everything idle) = uncovered global latency; depth-1 work (~400cy) <
//    HBM latency (~900cy). Costs 8 VGPRs (at 40, free).
//  - 4-deep RMW chain kept: R14 proved chain depth was NOT the binding cost
//    (depth/4 at 4x blocks was 1.5x SLOWER); per-block amortization wins.
// ---------------------------------------------------------------------------
__global__ __launch_bounds__(256) void pass1_kernel(
    const float* __restrict__ input, const int* __restrict__ target,
    float* __restrict__ sums, float* __restrict__ counts)
{
    __shared__ float buk[C_INST][256];   // 24.6 KB -> 6 blocks/CU (as before)
    __shared__ float crow[4][C_INST];
    const int tid   = threadIdx.x;
    const int lane  = tid & 63;
    const int wv    = tid >> 6;
    const int chunk = blockIdx.x;
    const int eg    = blockIdx.y;        // 0..15 = embedding dim
    const int b     = blockIdx.z;

    #pragma unroll
    for (int c = 0; c < C_INST; ++c) buk[c][tid] = 0.f;   // own column: no sync

    const int4* __restrict__ tgt4 = (const int4*)(target + (size_t)b * HW_N);
    const float4* __restrict__ src4 =
        (const float4*)(input + ((size_t)b * E_DIM + eg) * HW_N);
    const int gbase = chunk * 256 * P1_ITER + tid;

    int scnt[C_INST];
    #pragma unroll
    for (int c = 0; c < C_INST; ++c) scnt[c] = 0;

    int4   lab0 = tgt4[gbase];
    float4 x0   = src4[gbase];
    int4   lab1 = tgt4[gbase + 256];
    float4 x1   = src4[gbase + 256];
    #pragma unroll
    for (int it = 0; it < P1_ITER; ++it) {
        const int4   lc = lab0;
        const float4 xc = x0;
        lab0 = lab1; x0 = x1;
        if (it + 2 < P1_ITER) {          // depth-2 register prefetch
            lab1 = tgt4[gbase + (it + 2) * 256];
            x1   = src4[gbase + (it + 2) * 256];
        }
        buk[lc.x][tid] += xc.x;          // bank = tid%32 regardless of label
        buk[lc.y][tid] += xc.y;
        buk[lc.z][tid] += xc.z;
        buk[lc.w][tid] += xc.w;
        if (eg < CNT_PL && it == eg) {   // uniform branch: count this slice once
            #pragma unroll
            for (int c = 0; c < C_INST; ++c) {
                scnt[c] += (int)__popcll(__ballot(lc.x == c))
                         + (int)__popcll(__ballot(lc.y == c))
                         + (int)__popcll(__ballot(lc.z == c))
                         + (int)__popcll(__ballot(lc.w == c));
            }
        }
    }
    if (lane == 0) {
        #pragma unroll
        for (int c = 0; c < C_INST; ++c) crow[wv][c] = (float)scnt[c];
    }
    __syncthreads();

    // reduce 256 columns -> 24 class sums; 8 threads/class; per-class rotation
    // (k+c)&31 keeps each wave's 64 reads at 2-way bank alias (= free).
    if (tid < 8 * C_INST) {
        const int c  = tid >> 3;
        const int r0 = tid & 7;
        float s = 0.f;
        #pragma unroll
        for (int k = 0; k < 32; ++k)
            s += buk[c][r0 + 8 * ((k + c) & 31)];
        s += __shfl_xor(s, 1, 64);
        s += __shfl_xor(s, 2, 64);
        s += __shfl_xor(s, 4, 64);
        if (r0 == 0)
            unsafeAtomicAdd(&sums[((size_t)b * E_DIM + eg) * C_INST + c], s);
    }
    if (eg < CNT_PL && tid < C_INST) {
        const float s = crow[0][tid] + crow[1][tid] + crow[2][tid] + crow[3][tid];
        unsafeAtomicAdd(&counts[b * C_INST + tid], s);
    }
}

// ---------------------------------------------------------------------------
// Pass 2 (R15): R0-proven float4 body; mu packed as float4 rows -> 16
// ds_read_b128 per thread instead of 64 scalar gathers. Row stride 5 float4
// (80 B): label residues spread over 8 bank-quads (~3-way worst case).
// Per-block partial to a DISTINCT slot; read by final kernel (boundary =
// visibility; no agent atomics — R13 lesson).
// ---------------------------------------------------------------------------
__global__ __launch_bounds__(256) void pass2_kernel(
    const float* __restrict__ input, const int* __restrict__ target,
    const float* __restrict__ sums, const float* __restrict__ counts,
    float* __restrict__ partials)
{
    __shared__ float4 mu4[C_INST][5];    // [c][e4], e4<4 used; row 80 B
    __shared__ float w_l[C_INST];
    __shared__ float redw[4];
    const int tid  = threadIdx.x;
    const int lane = tid & 63;
    const int wv   = tid >> 6;
    const int b    = blockIdx.y;

    if (tid < C_INST) {
        const float cv = counts[b * C_INST + tid];
        w_l[tid] = (cv > 0.f) ? 1.f / cv : 0.f;
    }
    __syncthreads();
    for (int i = tid; i < E_DIM * C_INST; i += 256) {
        const int e = i / C_INST, c = i % C_INST;
        ((float*)&mu4[c][0])[e] =
            sums[((size_t)b * E_DIM + e) * C_INST + c] * w_l[c];
    }
    __syncthreads();

    const int g = blockIdx.x * 256 + tid;    // 256 blocks/batch, float4 groups
    const int4 lab4 = ((const int4*)(target + (size_t)b * HW_N))[g];
    const float4* __restrict__ src4 =
        (const float4*)(input + (size_t)b * E_DIM * NG * 4);

    float4 xv[E_DIM];
    #pragma unroll
    for (int e = 0; e < E_DIM; ++e)
        xv[e] = src4[(size_t)e * NG + g];

    float d2[4] = {0.f, 0.f, 0.f, 0.f};
    #pragma unroll
    for (int e4 = 0; e4 < 4; ++e4) {
        const float4 mx = mu4[lab4.x][e4];
        const float4 my = mu4[lab4.y][e4];
        const float4 mz = mu4[lab4.z][e4];
        const float4 mw = mu4[lab4.w][e4];
        float df;
        df = xv[4*e4+0].x - mx.x; d2[0] = fmaf(df, df, d2[0]);
        df = xv[4*e4+1].x - mx.y; d2[0] = fmaf(df, df, d2[0]);
        df = xv[4*e4+2].x - mx.z; d2[0] = fmaf(df, df, d2[0]);
        df = xv[4*e4+3].x - mx.w; d2[0] = fmaf(df, df, d2[0]);
        df = xv[4*e4+0].y - my.x; d2[1] = fmaf(df, df, d2[1]);
        df = xv[4*e4+1].y - my.y; d2[1] = fmaf(df, df, d2[1]);
        df = xv[4*e4+2].y - my.z; d2[1] = fmaf(df, df, d2[1]);
        df = xv[4*e4+3].y - my.w; d2[1] = fmaf(df, df, d2[1]);
        df = xv[4*e4+0].z - mz.x; d2[2] = fmaf(df, df, d2[2]);
        df = xv[4*e4+1].z - mz.y; d2[2] = fmaf(df, df, d2[2]);
        df = xv[4*e4+2].z - mz.z; d2[2] = fmaf(df, df, d2[2]);
        df = xv[4*e4+3].z - mz.w; d2[2] = fmaf(df, df, d2[2]);
        df = xv[4*e4+0].w - mw.x; d2[3] = fmaf(df, df, d2[3]);
        df = xv[4*e4+1].w - mw.y; d2[3] = fmaf(df, df, d2[3]);
        df = xv[4*e4+2].w - mw.z; d2[3] = fmaf(df, df, d2[3]);
        df = xv[4*e4+3].w - mw.w; d2[3] = fmaf(df, df, d2[3]);
    }

    float vloc = 0.f;
    {
        const int lp[4] = {lab4.x, lab4.y, lab4.z, lab4.w};
        #pragma unroll
        for (int p = 0; p < 4; ++p) {
            const float h = fmaxf(sqrtf(d2[p]) - DELTA_VAR, 0.f);
            vloc = fmaf(h * h, w_l[lp[p]], vloc);
        }
    }
    #pragma unroll
    for (int m = 1; m < 64; m <<= 1) vloc += __shfl_xor(vloc, m, 64);
    if (lane == 0) redw[wv] = vloc;
    __syncthreads();
    if (tid == 0)
        partials[b * P2_BX + blockIdx.x] = redw[0] + redw[1] + redw[2] + redw[3];
}

// ---------------------------------------------------------------------------
// Final (R10-proven): sum 1024 partials + pairwise distance + regularizer.
// ---------------------------------------------------------------------------
__global__ __launch_bounds__(256) void final_kernel(
    const float* __restrict__ sums, const float* __restrict__ counts,
    const float* __restrict__ partials, float* __restrict__ out)
{
    __shared__ float mu[B_SZ][C_INST][E_DIM];
    __shared__ float red[256];
    const int tid = threadIdx.x;

    for (int i = tid; i < B_SZ * C_INST * E_DIM; i += 256) {
        const int b = i / (C_INST * E_DIM);
        const int r = i % (C_INST * E_DIM);
        const int e = r / C_INST, c = r % C_INST;
        const float cv = counts[b * C_INST + c];
        mu[b][c][e] = (cv > 0.f)
            ? sums[((size_t)b * E_DIM + e) * C_INST + c] / cv : 0.f;
    }
    __syncthreads();

    float acc = 0.f;
    // variance partials (1024 slots, 4 per thread)
    #pragma unroll
    for (int i = 0; i < P2_TOTAL / 256; ++i)
        acc += partials[i * 256 + tid] * (ALPHA_W / (B_SZ * C_INST));
    // regularizer
    for (int i = tid; i < B_SZ * C_INST; i += 256) {
        const int b = i / C_INST, c = i % C_INST;
        float n2 = 0.f;
        #pragma unroll
        for (int e = 0; e < E_DIM; ++e) n2 += mu[b][c][e] * mu[b][c][e];
        acc += GAMMA_W * sqrtf(n2) * (1.0f / (B_SZ * C_INST));
    }
    // pairwise repulsion
    for (int i = tid; i < B_SZ * C_INST * C_INST; i += 256) {
        const int b  = i / (C_INST * C_INST);
        const int r  = i % (C_INST * C_INST);
        const int c1 = r / C_INST, c2 = r % C_INST;
        if (c1 != c2) {
            float d2 = 0.f;
            #pragma unroll
            for (int e = 0; e < E_DIM; ++e) {
                const float d = mu[b][c1][e] - mu[b][c2][e];
                d2 += d * d;
            }
            const float h = fmaxf(2.0f * DELTA_DIST - sqrtf(d2), 0.f);
            acc += BETA_W * h * h * (1.0f / (B_SZ * C_INST * (C_INST - 1)));
        }
    }

    red[tid] = acc;
    __syncthreads();
    for (int s = 128; s > 0; s >>= 1) {
        if (tid < s) red[tid] += red[tid + s];
        __syncthreads();
    }
    if (tid == 0) out[0] = red[0];
}

extern "C" void kernel_launch(void* const* d_in, const int* in_sizes, int n_in,
                              void* d_out, int out_size, void* d_ws, size_t ws_size,
                              hipStream_t stream)
{
    const float* input  = (const float*)d_in[0];
    const int*   target = (const int*)d_in[1];

    float* sums     = (float*)d_ws;                         // B*E*C ([b][e][c])
    float* counts   = sums + B_SZ * E_DIM * C_INST;         // B*C
    float* partials = counts + B_SZ * C_INST;               // 1024 (distinct slots)
    const size_t ws_zero_bytes =
        (size_t)(B_SZ * E_DIM * C_INST + B_SZ * C_INST) * sizeof(float);
    hipMemsetAsync(d_ws, 0, ws_zero_bytes, stream);

    pass1_kernel<<<dim3(P1_NB, E_DIM, B_SZ), 256, 0, stream>>>(input, target, sums, counts);
    pass2_kernel<<<dim3(P2_BX, B_SZ), 256, 0, stream>>>(input, target, sums, counts, partials);
    final_kernel<<<1, 256, 0, stream>>>(sums, counts, partials, (float*)d_out);
}